// Round 1
// baseline (174.648 us; speedup 1.0000x reference)
//
#include <hip/hip_runtime.h>

#define BB 32
#define SS 512
#define HH 256
#define NBINS 256
#define TMAX 4096

// Boundary i of np.linspace(vmin, vmax, 256) computed as NumPy does:
// step = (vmax-vmin)/255 (f64); b[i] = i*step + vmin (f64); b[255] = vmax.
__device__ __forceinline__ double boundary(int i, double vmin, double vmax, double step) {
    if (i == NBINS - 1) return vmax;
    return (double)i * step + vmin;
}

// searchsorted(boundaries, clip(v,vmin,vmax), side='left'), clipped to [0,255]
__device__ __forceinline__ int quantize_bin(float v, float vminf, float vmaxf) {
    v = fminf(fmaxf(v, vminf), vmaxf);
    double vd = (double)v;
    double vmin = (double)vminf, vmax = (double)vmaxf;
    double step = (vmax - vmin) / (double)(NBINS - 1);
    int g = (int)ceil((vd - vmin) / step);
    g = max(0, min(NBINS - 1, g));
    // enforce: smallest g with vd <= b[g]
    while (g > 0 && vd <= boundary(g - 1, vmin, vmax, step)) g--;
    while (g < NBINS - 1 && vd > boundary(g, vmin, vmax, step)) g++;
    return g;
}

// One block per batch. 512 threads (= S).
__global__ __launch_bounds__(512)
void prep_kernel(const float* __restrict__ pitch,
                 const float* __restrict__ energy,
                 const float* __restrict__ dur,
                 int* __restrict__ idx_map,   // [B*TMAX], -1 = padded frame
                 int* __restrict__ pbins,     // [B*S]
                 int* __restrict__ ebins) {   // [B*S]
    int b = blockIdx.x;
    int s = threadIdx.x;
    __shared__ int cum[SS];

    int tok = b * SS + s;
    // bins
    pbins[tok] = quantize_bin(pitch[tok], 50.0f, 400.0f);
    ebins[tok] = quantize_bin(energy[tok], 0.0f, 1.0f);
    // durations: round half-to-even (np.round), clamp >= 1
    int d = (int)rintf(dur[tok]);
    if (d < 1) d = 1;
    cum[s] = d;
    __syncthreads();

    // Hillis-Steele inclusive scan over 512 elements
    for (int off = 1; off < SS; off <<= 1) {
        int add = (s >= off) ? cum[s - off] : 0;
        __syncthreads();
        cum[s] += add;
        __syncthreads();
    }
    int total = cum[SS - 1];

    // frame -> token map: searchsorted(cum, t, 'right') = first j with cum[j] > t
    for (int t = s; t < TMAX; t += SS) {
        int j;
        if (t >= total) {
            j = -1;
        } else {
            int lo = 0, hi = SS;
            while (lo < hi) {
                int m = (lo + hi) >> 1;
                if (cum[m] <= t) lo = m + 1; else hi = m;
            }
            j = (lo > SS - 1) ? (SS - 1) : lo;
        }
        idx_map[b * TMAX + t] = j;
    }
}

// One wave (64 lanes) per output frame row; lane handles one float4 (H=256 = 64*4).
__global__ __launch_bounds__(256)
void gather_kernel(const float* __restrict__ enc,
                   const float* __restrict__ ptab,
                   const float* __restrict__ etab,
                   const int* __restrict__ idx_map,
                   const int* __restrict__ pbins,
                   const int* __restrict__ ebins,
                   float* __restrict__ out) {
    int row = blockIdx.x * 4 + (threadIdx.x >> 6);   // [0, B*TMAX)
    int lane = threadIdx.x & 63;
    int b = row >> 12;                               // TMAX = 4096 = 2^12
    int j = idx_map[row];

    float4* outv = reinterpret_cast<float4*>(out + (size_t)row * HH) + lane;
    if (j < 0) {
        *outv = make_float4(0.f, 0.f, 0.f, 0.f);
        return;
    }
    int tok = b * SS + j;
    int pb = pbins[tok];
    int eb = ebins[tok];
    const float4 e = reinterpret_cast<const float4*>(enc  + (size_t)tok * HH)[lane];
    const float4 p = reinterpret_cast<const float4*>(ptab + (size_t)pb  * HH)[lane];
    const float4 q = reinterpret_cast<const float4*>(etab + (size_t)eb  * HH)[lane];
    // match reference association: (enc + pt) + et
    float4 r;
    r.x = (e.x + p.x) + q.x;
    r.y = (e.y + p.y) + q.y;
    r.z = (e.z + p.z) + q.z;
    r.w = (e.w + p.w) + q.w;
    *outv = r;
}

extern "C" void kernel_launch(void* const* d_in, const int* in_sizes, int n_in,
                              void* d_out, int out_size, void* d_ws, size_t ws_size,
                              hipStream_t stream) {
    const float* enc    = (const float*)d_in[0];  // [B,S,H]
    const float* pitch  = (const float*)d_in[1];  // [B,S]
    const float* energy = (const float*)d_in[2];  // [B,S]
    const float* dur    = (const float*)d_in[3];  // [B,S]
    const float* ptab   = (const float*)d_in[4];  // [256,H]
    const float* etab   = (const float*)d_in[5];  // [256,H]
    float* out = (float*)d_out;                   // [B,TMAX,H]

    char* ws = (char*)d_ws;
    int* idx_map = (int*)ws;                              // B*TMAX ints  = 512 KB
    int* pbins   = (int*)(ws + (size_t)BB * TMAX * 4);    // B*S ints     = 64 KB
    int* ebins   = pbins + BB * SS;                       // B*S ints     = 64 KB

    prep_kernel<<<BB, SS, 0, stream>>>(pitch, energy, dur, idx_map, pbins, ebins);

    int rows = BB * TMAX;
    gather_kernel<<<rows / 4, 256, 0, stream>>>(enc, ptab, etab, idx_map, pbins, ebins, out);
}

// Round 2
// 173.403 us; speedup vs baseline: 1.0072x; 1.0072x over previous
//
#include <hip/hip_runtime.h>

#define BB 32
#define SS 512
#define HH 256
#define NBINS 256
#define TMAX 4096
#define ROWS_PER_WAVE 16

// Boundary i of np.linspace(vmin, vmax, 256) computed as NumPy does:
// step = (vmax-vmin)/255 (f64); b[i] = i*step + vmin (f64); b[255] = vmax.
__device__ __forceinline__ double boundary(int i, double vmin, double vmax, double step) {
    if (i == NBINS - 1) return vmax;
    return (double)i * step + vmin;
}

// searchsorted(boundaries, clip(v,vmin,vmax), side='left'), clipped to [0,255]
__device__ __forceinline__ int quantize_bin(float v, float vminf, float vmaxf) {
    v = fminf(fmaxf(v, vminf), vmaxf);
    double vd = (double)v;
    double vmin = (double)vminf, vmax = (double)vmaxf;
    double step = (vmax - vmin) / (double)(NBINS - 1);
    int g = (int)ceil((vd - vmin) / step);
    g = max(0, min(NBINS - 1, g));
    // enforce: smallest g with vd <= b[g]
    while (g > 0 && vd <= boundary(g - 1, vmin, vmax, step)) g--;
    while (g < NBINS - 1 && vd > boundary(g, vmin, vmax, step)) g++;
    return g;
}

// One block per batch. 512 threads (= S).
// Writes packed map[b*TMAX + t]: j | pbin<<9 | ebin<<17, or -1 for padded frame.
__global__ __launch_bounds__(512)
void prep_kernel(const float* __restrict__ pitch,
                 const float* __restrict__ energy,
                 const float* __restrict__ dur,
                 int* __restrict__ map) {
    int b = blockIdx.x;
    int s = threadIdx.x;
    __shared__ int cum[SS];
    __shared__ int pb_sh[SS];
    __shared__ int eb_sh[SS];

    int tok = b * SS + s;
    pb_sh[s] = quantize_bin(pitch[tok], 50.0f, 400.0f);
    eb_sh[s] = quantize_bin(energy[tok], 0.0f, 1.0f);
    // durations: round half-to-even (np.round), clamp >= 1
    int d = (int)rintf(dur[tok]);
    if (d < 1) d = 1;
    cum[s] = d;
    __syncthreads();

    // Hillis-Steele inclusive scan over 512 elements
    for (int off = 1; off < SS; off <<= 1) {
        int add = (s >= off) ? cum[s - off] : 0;
        __syncthreads();
        cum[s] += add;
        __syncthreads();
    }
    int total = cum[SS - 1];

    // frame -> token map: searchsorted(cum, t, 'right') = first j with cum[j] > t
    for (int t = s; t < TMAX; t += SS) {
        int packed;
        if (t >= total) {
            packed = -1;
        } else {
            int lo = 0, hi = SS;
            while (lo < hi) {
                int m = (lo + hi) >> 1;
                if (cum[m] <= t) lo = m + 1; else hi = m;
            }
            int j = (lo > SS - 1) ? (SS - 1) : lo;
            packed = j | (pb_sh[j] << 9) | (eb_sh[j] << 17);
        }
        map[b * TMAX + t] = packed;
    }
}

// Each wave handles ROWS_PER_WAVE consecutive frames; lane handles one float4
// (H=256 = 64 lanes * 4). Runs of identical tokens reuse the cached register
// value (avg run length ~4.5), and consecutive rows stay on one CU/XCD.
__global__ __launch_bounds__(256)
void gather_kernel(const float* __restrict__ enc,
                   const float* __restrict__ ptab,
                   const float* __restrict__ etab,
                   const int* __restrict__ map,
                   float* __restrict__ out) {
    int wave = blockIdx.x * 4 + (threadIdx.x >> 6);
    int lane = threadIdx.x & 63;
    int row0 = wave * ROWS_PER_WAVE;                 // 16 | 4096, so one batch per wave
    int b = row0 >> 12;                              // TMAX = 4096 = 2^12

    // one coalesced load of this wave's 16 map entries, broadcast via shfl
    int my_packed = (lane < ROWS_PER_WAVE) ? map[row0 + lane] : 0;

    int last_packed = -2;
    float4 val = make_float4(0.f, 0.f, 0.f, 0.f);
    float4* outv = reinterpret_cast<float4*>(out + (size_t)row0 * HH) + lane;

    #pragma unroll
    for (int r = 0; r < ROWS_PER_WAVE; ++r) {
        int packed = __shfl(my_packed, r);
        if (packed != last_packed) {
            if (packed < 0) {
                val = make_float4(0.f, 0.f, 0.f, 0.f);
            } else {
                int j  = packed & 511;
                int pb = (packed >> 9) & 255;
                int eb = (packed >> 17) & 255;
                int tok = b * SS + j;
                const float4 e = reinterpret_cast<const float4*>(enc  + (size_t)tok * HH)[lane];
                const float4 p = reinterpret_cast<const float4*>(ptab + (size_t)pb  * HH)[lane];
                const float4 q = reinterpret_cast<const float4*>(etab + (size_t)eb  * HH)[lane];
                // match reference association: (enc + pt) + et
                val.x = (e.x + p.x) + q.x;
                val.y = (e.y + p.y) + q.y;
                val.z = (e.z + p.z) + q.z;
                val.w = (e.w + p.w) + q.w;
            }
            last_packed = packed;
        }
        outv[(size_t)r * (HH / 4)] = val;
    }
}

extern "C" void kernel_launch(void* const* d_in, const int* in_sizes, int n_in,
                              void* d_out, int out_size, void* d_ws, size_t ws_size,
                              hipStream_t stream) {
    const float* enc    = (const float*)d_in[0];  // [B,S,H]
    const float* pitch  = (const float*)d_in[1];  // [B,S]
    const float* energy = (const float*)d_in[2];  // [B,S]
    const float* dur    = (const float*)d_in[3];  // [B,S]
    const float* ptab   = (const float*)d_in[4];  // [256,H]
    const float* etab   = (const float*)d_in[5];  // [256,H]
    float* out = (float*)d_out;                   // [B,TMAX,H]

    int* map = (int*)d_ws;                        // B*TMAX ints = 512 KB

    prep_kernel<<<BB, SS, 0, stream>>>(pitch, energy, dur, map);

    int waves = (BB * TMAX) / ROWS_PER_WAVE;      // 8192
    gather_kernel<<<waves / 4, 256, 0, stream>>>(enc, ptab, etab, map, out);
}